// Round 3
// baseline (383.931 us; speedup 1.0000x reference)
//
#include <hip/hip_runtime.h>

typedef unsigned short u16;
typedef unsigned int u32;

typedef __attribute__((ext_vector_type(8))) short bf16x8;
typedef __attribute__((ext_vector_type(4))) float f32x4;

static __device__ __forceinline__ u16 f2bf(float f) {
    u32 u = __float_as_uint(f);
    u32 r = (u + 0x7FFFu + ((u >> 16) & 1u)) >> 16;
    return (u16)r;
}
static __device__ __forceinline__ float bf2f(u16 h) {
    return __uint_as_float(((u32)h) << 16);
}

// ---------------- fp32 -> bf16 convert (vectorized) ----------------
__global__ __launch_bounds__(256) void convert_bf16_kernel(const float* __restrict__ x,
                                                           u16* __restrict__ y, int n4) {
    int i = blockIdx.x * 256 + threadIdx.x;
    if (i < n4) {
        float4 v = ((const float4*)x)[i];
        ushort4 o;
        o.x = f2bf(v.x); o.y = f2bf(v.y); o.z = f2bf(v.z); o.w = f2bf(v.w);
        ((ushort4*)y)[i] = o;
    }
}

// ---------------- W [K,N] fp32 -> W^T [N,K] bf16 ----------------
__global__ __launch_bounds__(256) void transpose_to_bf16_kernel(const float* __restrict__ W,
                                                                u16* __restrict__ WT, int D) {
    __shared__ float t[32][33];
    int bx = blockIdx.x, by = blockIdx.y;
    int tx = threadIdx.x, ty = threadIdx.y;
#pragma unroll
    for (int i = ty; i < 32; i += 8)
        t[i][tx] = W[(long)(by * 32 + i) * D + bx * 32 + tx];
    __syncthreads();
#pragma unroll
    for (int i = ty; i < 32; i += 8)
        WT[(long)(bx * 32 + i) * D + by * 32 + tx] = f2bf(t[tx][i]);
}

__global__ __launch_bounds__(256) void concat_bias_kernel(const float* __restrict__ a,
                                                          const float* __restrict__ b,
                                                          float* __restrict__ o, int n) {
    int i = blockIdx.x * 256 + threadIdx.x;
    if (i < 2 * n) o[i] = (i < n) ? a[i] : b[i - n];
}

// ================= 256x256-tile GEMM, 512 threads, BK=32, double-buffered =================
// C[m,n] = scale*sum_k A[m,k]*B[n,k] (+bias)(+mask). Grid: (N/256, M/256, batch).
// Keep the N-dim (size 8) in blockIdx.x: XCD = linear%8 = bx, so each XCD keeps one
// 512 KB B-panel hot in its private L2 while streaming A -> fewer L3/HBM re-reads.
// Wave tile 64x128 (4x8 16x16x32 accs): LDS bytes/FLOP = (64+128)/(64*128*2) = 0.0229,
// 1.33x less than the 64x64 wave tile -> below the LDS-BW ceiling at the MFMA rate.
// Chunk swizzle sw(row)=(row^(row>>2))&3 keeps ds_read_b128 at 2-way (free) conflicts
// while the global_load_lds destination stays wave-uniform + lane-ordered.
__global__ __launch_bounds__(512, 2) void gemm256_kernel(
    const u16* __restrict__ A, int lda, long sA,
    const u16* __restrict__ B, int ldb, long sB,
    void* __restrict__ C, int ldc, long sC, int c_bf16,
    const float* __restrict__ bias, int bias_mode,
    const float* __restrict__ madd, int mask_ld,
    float scale, int K) {
    __shared__ __align__(16) u16 As[2][256 * 32];
    __shared__ __align__(16) u16 Bs[2][256 * 32];
    const int b = blockIdx.z;
    const u16* Ab = A + (long)b * sA;
    const u16* Bb = B + (long)b * sB;
    const int tm = blockIdx.y * 256, tn = blockIdx.x * 256;
    const int tid = threadIdx.x, wave = tid >> 6, lane = tid & 63;
    const int wm = (wave & 3) * 64, wn = (wave >> 2) * 128;
    const int lr = lane >> 2, c = lane & 3;    // staging: row-in-group, 16B-chunk
    const int fm = lane & 15, fq = lane >> 4;  // fragment: m/n index, quad

    f32x4 acc[4][8];
#pragma unroll
    for (int i = 0; i < 4; i++)
#pragma unroll
        for (int j = 0; j < 8; j++) acc[i][j] = (f32x4){0.f, 0.f, 0.f, 0.f};

    const int T = K >> 5;

    auto stage = [&](int t, int buf) {
#pragma unroll
        for (int r = 0; r < 2; r++) {
            const int rl = r * 128 + wave * 16;  // wave-uniform LDS row base
            const int rowl = rl + lr;            // this lane's row
            const int kc = (t << 5) + (((c ^ ((rowl ^ (rowl >> 2)) & 3)) << 3));
            const u16* ga = Ab + (long)(tm + rowl) * lda + kc;
            const u16* gb = Bb + (long)(tn + rowl) * ldb + kc;
            __builtin_amdgcn_global_load_lds((const __attribute__((address_space(1))) void*)ga,
                                             (__attribute__((address_space(3))) void*)&As[buf][rl * 32],
                                             16, 0, 0);
            __builtin_amdgcn_global_load_lds((const __attribute__((address_space(1))) void*)gb,
                                             (__attribute__((address_space(3))) void*)&Bs[buf][rl * 32],
                                             16, 0, 0);
        }
    };

    stage(0, 0);
    __syncthreads();
    for (int t = 0; t < T; t++) {
        const int cur = t & 1;
        if (t + 1 < T) stage(t + 1, cur ^ 1);
        bf16x8 af[4], bfr[8];
#pragma unroll
        for (int i = 0; i < 4; i++) {
            int row = wm + i * 16 + fm;
            af[i] = *(const bf16x8*)&As[cur][row * 32 + (((fq ^ ((row ^ (row >> 2)) & 3))) << 3)];
        }
#pragma unroll
        for (int j = 0; j < 8; j++) {
            int row = wn + j * 16 + fm;
            bfr[j] = *(const bf16x8*)&Bs[cur][row * 32 + (((fq ^ ((row ^ (row >> 2)) & 3))) << 3)];
        }
#pragma unroll
        for (int i = 0; i < 4; i++)
#pragma unroll
            for (int j = 0; j < 8; j++)
                acc[i][j] = __builtin_amdgcn_mfma_f32_16x16x32_bf16(af[i], bfr[j], acc[i][j], 0, 0, 0);
        if (t + 1 < T) __syncthreads();
    }

#pragma unroll
    for (int i = 0; i < 4; i++) {
#pragma unroll
        for (int j = 0; j < 8; j++) {
#pragma unroll
            for (int r = 0; r < 4; r++) {
                int row = tm + wm + i * 16 + fq * 4 + r;
                int col = tn + wn + j * 16 + fm;
                float v = acc[i][j][r] * scale;
                if (bias_mode == 1) v += bias[col];
                else if (bias_mode == 2) v += bias[row];
                if (madd) v += madd[(long)row * mask_ld + col];
                if (c_bf16)
                    ((u16*)C)[(long)b * sC + (long)row * ldc + col] = f2bf(v);
                else
                    ((float*)C)[(long)b * sC + (long)row * ldc + col] = v;
            }
        }
    }
}

// ================= 128x128-tile GEMM (R2), used for VT / PV =================
__global__ __launch_bounds__(256, 2) void gemm_bt_kernel(
    const u16* __restrict__ A, int lda, long sA,
    const u16* __restrict__ B, int ldb, long sB,
    void* __restrict__ C, int ldc, long sC, int c_bf16,
    const float* __restrict__ bias, int bias_mode,
    const float* __restrict__ madd, int mask_ld,
    float scale, int K) {
    __shared__ __align__(16) u16 As[2][128 * 64];
    __shared__ __align__(16) u16 Bs[2][128 * 64];
    const int b = blockIdx.z;
    const u16* Ab = A + (long)b * sA;
    const u16* Bb = B + (long)b * sB;
    const int tm = blockIdx.y * 128, tn = blockIdx.x * 128;
    const int tid = threadIdx.x, wave = tid >> 6, lane = tid & 63;
    const int wm = (wave >> 1) * 64, wn = (wave & 1) * 64;
    const int lr = lane >> 3, lc = lane & 7;
    const int scz = ((lc ^ lr) << 3);
    const int fm = lane & 15, fq = lane >> 4;

    f32x4 acc[4][4];
#pragma unroll
    for (int i = 0; i < 4; i++)
#pragma unroll
        for (int j = 0; j < 4; j++) acc[i][j] = (f32x4){0.f, 0.f, 0.f, 0.f};

    const int T = K >> 6;

    auto stage = [&](int t, int buf) {
#pragma unroll
        for (int i = 0; i < 4; i++) {
            int row = i * 32 + wave * 8;
            const u16* ga = Ab + (long)(tm + row + lr) * lda + (t << 6) + scz;
            const u16* gb = Bb + (long)(tn + row + lr) * ldb + (t << 6) + scz;
            __builtin_amdgcn_global_load_lds((const __attribute__((address_space(1))) void*)ga,
                                             (__attribute__((address_space(3))) void*)&As[buf][row * 64],
                                             16, 0, 0);
            __builtin_amdgcn_global_load_lds((const __attribute__((address_space(1))) void*)gb,
                                             (__attribute__((address_space(3))) void*)&Bs[buf][row * 64],
                                             16, 0, 0);
        }
    };

    stage(0, 0);
    __syncthreads();
    for (int t = 0; t < T; t++) {
        const int cur = t & 1;
        if (t + 1 < T) stage(t + 1, cur ^ 1);
#pragma unroll
        for (int ks = 0; ks < 2; ks++) {
            bf16x8 af[4], bfr[4];
#pragma unroll
            for (int i = 0; i < 4; i++) {
                int row = wm + i * 16 + fm;
                af[i] = *(const bf16x8*)&As[cur][row * 64 + ((((ks << 2) + fq) ^ (fm & 7)) << 3)];
            }
#pragma unroll
            for (int j = 0; j < 4; j++) {
                int row = wn + j * 16 + fm;
                bfr[j] = *(const bf16x8*)&Bs[cur][row * 64 + ((((ks << 2) + fq) ^ (fm & 7)) << 3)];
            }
#pragma unroll
            for (int i = 0; i < 4; i++)
#pragma unroll
                for (int j = 0; j < 4; j++)
                    acc[i][j] = __builtin_amdgcn_mfma_f32_16x16x32_bf16(af[i], bfr[j], acc[i][j], 0, 0, 0);
        }
        if (t + 1 < T) __syncthreads();
    }

#pragma unroll
    for (int i = 0; i < 4; i++) {
#pragma unroll
        for (int j = 0; j < 4; j++) {
#pragma unroll
            for (int r = 0; r < 4; r++) {
                int row = tm + wm + i * 16 + fq * 4 + r;
                int col = tn + wn + j * 16 + fm;
                float v = acc[i][j][r] * scale;
                if (bias_mode == 1) v += bias[col];
                else if (bias_mode == 2) v += bias[row];
                if (madd) v += madd[(long)row * mask_ld + col];
                if (c_bf16)
                    ((u16*)C)[(long)b * sC + (long)row * ldc + col] = f2bf(v);
                else
                    ((float*)C)[(long)b * sC + (long)row * ldc + col] = v;
            }
        }
    }
}

// ---------------- in-place row softmax over 2048 bf16 cols ----------------
__global__ __launch_bounds__(256) void softmax_kernel(u16* __restrict__ s) {
    const long row = blockIdx.x;
    u16* p = s + row * 2048;
    const int tid = threadIdx.x;
    const int lane = tid & 63, wave = tid >> 6;
    __shared__ float redm[4], reds[4];

    uint4 raw = ((const uint4*)p)[tid];
    float v[8];
    v[0] = bf2f(raw.x & 0xffff); v[1] = bf2f(raw.x >> 16);
    v[2] = bf2f(raw.y & 0xffff); v[3] = bf2f(raw.y >> 16);
    v[4] = bf2f(raw.z & 0xffff); v[5] = bf2f(raw.z >> 16);
    v[6] = bf2f(raw.w & 0xffff); v[7] = bf2f(raw.w >> 16);

    float m = v[0];
#pragma unroll
    for (int k = 1; k < 8; k++) m = fmaxf(m, v[k]);
#pragma unroll
    for (int off = 32; off; off >>= 1) m = fmaxf(m, __shfl_xor(m, off));
    if (lane == 0) redm[wave] = m;
    __syncthreads();
    m = fmaxf(fmaxf(redm[0], redm[1]), fmaxf(redm[2], redm[3]));

    float sum = 0.f;
#pragma unroll
    for (int k = 0; k < 8; k++) { v[k] = __expf(v[k] - m); sum += v[k]; }
#pragma unroll
    for (int off = 32; off; off >>= 1) sum += __shfl_xor(sum, off);
    if (lane == 0) reds[wave] = sum;
    __syncthreads();
    sum = reds[0] + reds[1] + reds[2] + reds[3];
    float inv = 1.f / sum;

    uint4 o;
    o.x = (u32)f2bf(v[0] * inv) | ((u32)f2bf(v[1] * inv) << 16);
    o.y = (u32)f2bf(v[2] * inv) | ((u32)f2bf(v[3] * inv) << 16);
    o.z = (u32)f2bf(v[4] * inv) | ((u32)f2bf(v[5] * inv) << 16);
    o.w = (u32)f2bf(v[6] * inv) | ((u32)f2bf(v[7] * inv) << 16);
    ((uint4*)p)[tid] = o;
}

extern "C" void kernel_launch(void* const* d_in, const int* in_sizes, int n_in,
                              void* d_out, int out_size, void* d_ws, size_t ws_size,
                              hipStream_t stream) {
    const float* x    = (const float*)d_in[0];
    const float* mask = (const float*)d_in[1];
    const float* Wq   = (const float*)d_in[2];
    const float* bq   = (const float*)d_in[3];
    const float* Wk   = (const float*)d_in[4];
    const float* bk   = (const float*)d_in[5];
    const float* Wv   = (const float*)d_in[6];
    const float* bv   = (const float*)d_in[7];
    float* out = (float*)d_out;

    const int B = 4, S = 2048, D = 1024;
    const long MS = (long)B * S;  // 8192

    size_t need = (size_t)MS * D * 2          /* xb */
                + (size_t)(2 * D) * D * 2     /* wqkt */
                + (size_t)D * D * 2           /* wvt */
                + (size_t)(2 * D) * 4         /* bqk */
                + (size_t)MS * (2 * D) * 2    /* QK */
                + (size_t)D * MS * 2          /* VT */
                + (size_t)B * S * S * 2;      /* scores */
    if (ws_size < need) return;

    char* ws = (char*)d_ws;
    u16*  xb   = (u16*)ws;  ws += (long)MS * D * 2;
    u16*  wqkt = (u16*)ws;  ws += (long)(2 * D) * D * 2;
    u16*  wvt  = (u16*)ws;  ws += (long)D * D * 2;
    float* bqk = (float*)ws; ws += (long)(2 * D) * 4;
    u16*  QK   = (u16*)ws;  ws += (long)MS * (2 * D) * 2;
    u16*  VT   = (u16*)ws;  ws += (long)D * MS * 2;
    u16*  sc   = (u16*)ws;  ws += (long)B * S * S * 2;

    const float SCALE = 0.03125f;  // 1/sqrt(1024)

    // 1) convert x -> bf16
    convert_bf16_kernel<<<(int)((MS * D / 4 + 255) / 256), 256, 0, stream>>>(x, xb, (int)(MS * D / 4));
    // 2) transposed bf16 weights: wqkt rows [0,1024)=Wq^T, [1024,2048)=Wk^T; wvt=Wv^T
    dim3 tb(32, 8);
    transpose_to_bf16_kernel<<<dim3(32, 32), tb, 0, stream>>>(Wq, wqkt, D);
    transpose_to_bf16_kernel<<<dim3(32, 32), tb, 0, stream>>>(Wk, wqkt + (long)D * D, D);
    transpose_to_bf16_kernel<<<dim3(32, 32), tb, 0, stream>>>(Wv, wvt, D);
    concat_bias_kernel<<<8, 256, 0, stream>>>(bq, bk, bqk, D);

    // 3) fused QK projection: QK[m, 0:1024]=Q, QK[m, 1024:2048]=K   ([8192, 2048] bf16)
    //    grid (8, 32): bx (size 8) = N-tiles -> per-XCD B-panel reuse
    gemm256_kernel<<<dim3(2 * D / 256, (int)(MS / 256), 1), 512, 0, stream>>>(
        xb, D, 0, wqkt, D, 0, QK, 2 * D, 0, 1, bqk, 1, nullptr, 0, 1.0f, D);
    // 4) V^T[d, b*S+s] = sum_k WvT[d,k] xb[b*S+s,k] + bv[d]   ([1024, 8192] bf16)
    gemm_bt_kernel<<<dim3((int)(MS / 128), D / 128, 1), 256, 0, stream>>>(
        wvt, D, 0, xb, D, 0, VT, (int)MS, 0, 1, bv, 2, nullptr, 0, 1.0f, D);

    // 5) scores[b,q,k] = (Q.K^T)*scale + mask  -> bf16; grid (8, 8, 4)
    gemm256_kernel<<<dim3(S / 256, S / 256, B), 512, 0, stream>>>(
        QK, 2 * D, (long)S * 2 * D, QK + D, 2 * D, (long)S * 2 * D, sc, S, (long)S * S, 1,
        nullptr, 0, mask, S, SCALE, D);

    // 6) softmax in place over last dim
    softmax_kernel<<<B * S, 256, 0, stream>>>(sc);

    // 7) out[b,q,d] = sum_k attn[b,q,k] * VT[d, b*S+k]  (fp32 out)
    gemm_bt_kernel<<<dim3(D / 128, S / 128, B), 256, 0, stream>>>(
        sc, S, (long)S * S, VT, (int)MS, (long)S, out, D, (long)S * D, 0,
        nullptr, 0, nullptr, 0, 1.0f, S);
}

// Round 4
// 355.439 us; speedup vs baseline: 1.0802x; 1.0802x over previous
//
#include <hip/hip_runtime.h>

typedef unsigned short u16;
typedef unsigned int u32;

typedef __attribute__((ext_vector_type(8))) short bf16x8;
typedef __attribute__((ext_vector_type(4))) float f32x4;

static __device__ __forceinline__ u16 f2bf(float f) {
    u32 u = __float_as_uint(f);
    u32 r = (u + 0x7FFFu + ((u >> 16) & 1u)) >> 16;
    return (u16)r;
}
static __device__ __forceinline__ float bf2f(u16 h) {
    return __uint_as_float(((u32)h) << 16);
}

// ---------------- fp32 -> bf16 convert (vectorized) ----------------
__global__ __launch_bounds__(256) void convert_bf16_kernel(const float* __restrict__ x,
                                                           u16* __restrict__ y, int n4) {
    int i = blockIdx.x * 256 + threadIdx.x;
    if (i < n4) {
        float4 v = ((const float4*)x)[i];
        ushort4 o;
        o.x = f2bf(v.x); o.y = f2bf(v.y); o.z = f2bf(v.z); o.w = f2bf(v.w);
        ((ushort4*)y)[i] = o;
    }
}

// ---------------- W [K,N] fp32 -> W^T [N,K] bf16 ----------------
__global__ __launch_bounds__(256) void transpose_to_bf16_kernel(const float* __restrict__ W,
                                                                u16* __restrict__ WT, int D) {
    __shared__ float t[32][33];
    int bx = blockIdx.x, by = blockIdx.y;
    int tx = threadIdx.x, ty = threadIdx.y;
#pragma unroll
    for (int i = ty; i < 32; i += 8)
        t[i][tx] = W[(long)(by * 32 + i) * D + bx * 32 + tx];
    __syncthreads();
#pragma unroll
    for (int i = ty; i < 32; i += 8)
        WT[(long)(bx * 32 + i) * D + by * 32 + tx] = f2bf(t[tx][i]);
}

__global__ __launch_bounds__(256) void concat_bias_kernel(const float* __restrict__ a,
                                                          const float* __restrict__ b,
                                                          float* __restrict__ o, int n) {
    int i = blockIdx.x * 256 + threadIdx.x;
    if (i < 2 * n) o[i] = (i < n) ? a[i] : b[i - n];
}

// ================= 128x128-tile GEMM, BK=32, double-buffered, 32 KB LDS =================
// C[m,n] = scale*sum_k A[m,k]*B[n,k] (+bias)(+mask).
// 32 KB LDS + VGPR<=128 (launch_bounds 256,4) -> 4 blocks/CU resident: the vmcnt(0)
// barrier drain of one block overlaps MFMA of the other three (the R2->R4 occupancy fix;
// 64 KB dbuf allowed only 2 blocks/CU and measured 14% MfmaUtil with all pipes idle).
// Rows are 64 B (32 bf16, 4 x 16 B chunks); chunk swizzle sw(row)=(row^(row>>2))&3 makes
// both the staging writes and the ds_read_b128 fragment reads conflict-free while the
// global_load_lds destination stays wave-uniform + lane-ordered (lane*16 contiguous).
__global__ __launch_bounds__(256, 4) void gemm_bt_kernel(
    const u16* __restrict__ A, int lda, long sA,
    const u16* __restrict__ B, int ldb, long sB,
    void* __restrict__ C, int ldc, long sC, int c_bf16,
    const float* __restrict__ bias, int bias_mode,
    const float* __restrict__ madd, int mask_ld,
    float scale, int K) {
    __shared__ __align__(16) u16 As[2][128 * 32];
    __shared__ __align__(16) u16 Bs[2][128 * 32];
    const int b = blockIdx.z;
    const u16* Ab = A + (long)b * sA;
    const u16* Bb = B + (long)b * sB;
    const int tm = blockIdx.y * 128, tn = blockIdx.x * 128;
    const int tid = threadIdx.x, wave = tid >> 6, lane = tid & 63;
    const int wm = (wave >> 1) * 64, wn = (wave & 1) * 64;
    const int lr = lane >> 2, c = lane & 3;    // staging: row-in-16-group, 16B chunk
    const int fm = lane & 15, fq = lane >> 4;  // fragment: m/n index, quad

    f32x4 acc[4][4];
#pragma unroll
    for (int i = 0; i < 4; i++)
#pragma unroll
        for (int j = 0; j < 4; j++) acc[i][j] = (f32x4){0.f, 0.f, 0.f, 0.f};

    const int T = K >> 5;

    auto stage = [&](int t, int buf) {
#pragma unroll
        for (int r = 0; r < 2; r++) {
            const int rl = r * 64 + wave * 16;  // wave-uniform LDS row base
            const int row = rl + lr;            // this lane's row
            const int kc = (t << 5) + ((c ^ ((row ^ (row >> 2)) & 3)) << 3);
            const u16* ga = Ab + (long)(tm + row) * lda + kc;
            const u16* gb = Bb + (long)(tn + row) * ldb + kc;
            __builtin_amdgcn_global_load_lds((const __attribute__((address_space(1))) void*)ga,
                                             (__attribute__((address_space(3))) void*)&As[buf][rl * 32],
                                             16, 0, 0);
            __builtin_amdgcn_global_load_lds((const __attribute__((address_space(1))) void*)gb,
                                             (__attribute__((address_space(3))) void*)&Bs[buf][rl * 32],
                                             16, 0, 0);
        }
    };

    stage(0, 0);
    __syncthreads();
    for (int t = 0; t < T; t++) {
        const int cur = t & 1;
        if (t + 1 < T) stage(t + 1, cur ^ 1);
        bf16x8 af[4], bfr[4];
#pragma unroll
        for (int i = 0; i < 4; i++) {
            int row = wm + i * 16 + fm;
            af[i] = *(const bf16x8*)&As[cur][row * 32 + ((fq ^ ((row ^ (row >> 2)) & 3)) << 3)];
        }
#pragma unroll
        for (int j = 0; j < 4; j++) {
            int row = wn + j * 16 + fm;
            bfr[j] = *(const bf16x8*)&Bs[cur][row * 32 + ((fq ^ ((row ^ (row >> 2)) & 3)) << 3)];
        }
#pragma unroll
        for (int i = 0; i < 4; i++)
#pragma unroll
            for (int j = 0; j < 4; j++)
                acc[i][j] = __builtin_amdgcn_mfma_f32_16x16x32_bf16(af[i], bfr[j], acc[i][j], 0, 0, 0);
        if (t + 1 < T) __syncthreads();
    }

#pragma unroll
    for (int i = 0; i < 4; i++) {
#pragma unroll
        for (int j = 0; j < 4; j++) {
#pragma unroll
            for (int r = 0; r < 4; r++) {
                int row = tm + wm + i * 16 + fq * 4 + r;
                int col = tn + wn + j * 16 + fm;
                float v = acc[i][j][r] * scale;
                if (bias_mode == 1) v += bias[col];
                else if (bias_mode == 2) v += bias[row];
                if (madd) v += madd[(long)row * mask_ld + col];
                if (c_bf16)
                    ((u16*)C)[(long)b * sC + (long)row * ldc + col] = f2bf(v);
                else
                    ((float*)C)[(long)b * sC + (long)row * ldc + col] = v;
            }
        }
    }
}

// ---------------- in-place row softmax over 2048 bf16 cols ----------------
__global__ __launch_bounds__(256) void softmax_kernel(u16* __restrict__ s) {
    const long row = blockIdx.x;
    u16* p = s + row * 2048;
    const int tid = threadIdx.x;
    const int lane = tid & 63, wave = tid >> 6;
    __shared__ float redm[4], reds[4];

    uint4 raw = ((const uint4*)p)[tid];
    float v[8];
    v[0] = bf2f(raw.x & 0xffff); v[1] = bf2f(raw.x >> 16);
    v[2] = bf2f(raw.y & 0xffff); v[3] = bf2f(raw.y >> 16);
    v[4] = bf2f(raw.z & 0xffff); v[5] = bf2f(raw.z >> 16);
    v[6] = bf2f(raw.w & 0xffff); v[7] = bf2f(raw.w >> 16);

    float m = v[0];
#pragma unroll
    for (int k = 1; k < 8; k++) m = fmaxf(m, v[k]);
#pragma unroll
    for (int off = 32; off; off >>= 1) m = fmaxf(m, __shfl_xor(m, off));
    if (lane == 0) redm[wave] = m;
    __syncthreads();
    m = fmaxf(fmaxf(redm[0], redm[1]), fmaxf(redm[2], redm[3]));

    float sum = 0.f;
#pragma unroll
    for (int k = 0; k < 8; k++) { v[k] = __expf(v[k] - m); sum += v[k]; }
#pragma unroll
    for (int off = 32; off; off >>= 1) sum += __shfl_xor(sum, off);
    if (lane == 0) reds[wave] = sum;
    __syncthreads();
    sum = reds[0] + reds[1] + reds[2] + reds[3];
    float inv = 1.f / sum;

    uint4 o;
    o.x = (u32)f2bf(v[0] * inv) | ((u32)f2bf(v[1] * inv) << 16);
    o.y = (u32)f2bf(v[2] * inv) | ((u32)f2bf(v[3] * inv) << 16);
    o.z = (u32)f2bf(v[4] * inv) | ((u32)f2bf(v[5] * inv) << 16);
    o.w = (u32)f2bf(v[6] * inv) | ((u32)f2bf(v[7] * inv) << 16);
    ((uint4*)p)[tid] = o;
}

extern "C" void kernel_launch(void* const* d_in, const int* in_sizes, int n_in,
                              void* d_out, int out_size, void* d_ws, size_t ws_size,
                              hipStream_t stream) {
    const float* x    = (const float*)d_in[0];
    const float* mask = (const float*)d_in[1];
    const float* Wq   = (const float*)d_in[2];
    const float* bq   = (const float*)d_in[3];
    const float* Wk   = (const float*)d_in[4];
    const float* bk   = (const float*)d_in[5];
    const float* Wv   = (const float*)d_in[6];
    const float* bv   = (const float*)d_in[7];
    float* out = (float*)d_out;

    const int B = 4, S = 2048, D = 1024;
    const long MS = (long)B * S;  // 8192

    size_t need = (size_t)MS * D * 2          /* xb */
                + (size_t)(2 * D) * D * 2     /* wqkt */
                + (size_t)D * D * 2           /* wvt */
                + (size_t)(2 * D) * 4         /* bqk */
                + (size_t)MS * (2 * D) * 2    /* QK */
                + (size_t)D * MS * 2          /* VT */
                + (size_t)B * S * S * 2;      /* scores */
    if (ws_size < need) return;

    char* ws = (char*)d_ws;
    u16*  xb   = (u16*)ws;  ws += (long)MS * D * 2;
    u16*  wqkt = (u16*)ws;  ws += (long)(2 * D) * D * 2;
    u16*  wvt  = (u16*)ws;  ws += (long)D * D * 2;
    float* bqk = (float*)ws; ws += (long)(2 * D) * 4;
    u16*  QK   = (u16*)ws;  ws += (long)MS * (2 * D) * 2;
    u16*  VT   = (u16*)ws;  ws += (long)D * MS * 2;
    u16*  sc   = (u16*)ws;  ws += (long)B * S * S * 2;

    const float SCALE = 0.03125f;  // 1/sqrt(1024)

    // 1) convert x -> bf16
    convert_bf16_kernel<<<(int)((MS * D / 4 + 255) / 256), 256, 0, stream>>>(x, xb, (int)(MS * D / 4));
    // 2) transposed bf16 weights: wqkt rows [0,1024)=Wq^T, [1024,2048)=Wk^T; wvt=Wv^T
    dim3 tb(32, 8);
    transpose_to_bf16_kernel<<<dim3(32, 32), tb, 0, stream>>>(Wq, wqkt, D);
    transpose_to_bf16_kernel<<<dim3(32, 32), tb, 0, stream>>>(Wk, wqkt + (long)D * D, D);
    transpose_to_bf16_kernel<<<dim3(32, 32), tb, 0, stream>>>(Wv, wvt, D);
    concat_bias_kernel<<<8, 256, 0, stream>>>(bq, bk, bqk, D);

    // 3) fused QK projection: QK[m, 0:1024]=Q, QK[m, 1024:2048]=K   ([8192, 2048] bf16)
    gemm_bt_kernel<<<dim3(2 * D / 128, (int)(MS / 128), 1), 256, 0, stream>>>(
        xb, D, 0, wqkt, D, 0, QK, 2 * D, 0, 1, bqk, 1, nullptr, 0, 1.0f, D);
    // 4) V^T[d, b*S+s] = sum_k WvT[d,k] xb[b*S+s,k] + bv[d]   ([1024, 8192] bf16)
    gemm_bt_kernel<<<dim3((int)(MS / 128), D / 128, 1), 256, 0, stream>>>(
        wvt, D, 0, xb, D, 0, VT, (int)MS, 0, 1, bv, 2, nullptr, 0, 1.0f, D);

    // 5) scores[b,q,k] = (Q.K^T)*scale + mask  -> bf16, batched over z
    gemm_bt_kernel<<<dim3(S / 128, S / 128, B), 256, 0, stream>>>(
        QK, 2 * D, (long)S * 2 * D, QK + D, 2 * D, (long)S * 2 * D, sc, S, (long)S * S, 1,
        nullptr, 0, mask, S, SCALE, D);

    // 6) softmax in place over last dim
    softmax_kernel<<<B * S, 256, 0, stream>>>(sc);

    // 7) out[b,q,d] = sum_k attn[b,q,k] * VT[d, b*S+k]  (fp32 out)
    gemm_bt_kernel<<<dim3(D / 128, S / 128, B), 256, 0, stream>>>(
        sc, S, (long)S * S, VT, (int)MS, (long)S, out, D, (long)S * D, 0,
        nullptr, 0, nullptr, 0, 1.0f, S);
}

// Round 5
// 297.812 us; speedup vs baseline: 1.2892x; 1.1935x over previous
//
#include <hip/hip_runtime.h>

typedef unsigned short u16;
typedef unsigned int u32;

typedef __attribute__((ext_vector_type(8))) short bf16x8;
typedef __attribute__((ext_vector_type(4))) float f32x4;

static __device__ __forceinline__ u16 f2bf(float f) {
    u32 u = __float_as_uint(f);
    u32 r = (u + 0x7FFFu + ((u >> 16) & 1u)) >> 16;
    return (u16)r;
}
static __device__ __forceinline__ float bf2f(u16 h) {
    return __uint_as_float(((u32)h) << 16);
}
static __device__ __forceinline__ u32 pack2(float a, float b) {
    return (u32)f2bf(a) | ((u32)f2bf(b) << 16);
}

// ---------------- fp32 -> bf16 convert (vectorized) ----------------
__global__ __launch_bounds__(256) void convert_bf16_kernel(const float* __restrict__ x,
                                                           u16* __restrict__ y, int n4) {
    int i = blockIdx.x * 256 + threadIdx.x;
    if (i < n4) {
        float4 v = ((const float4*)x)[i];
        ushort4 o;
        o.x = f2bf(v.x); o.y = f2bf(v.y); o.z = f2bf(v.z); o.w = f2bf(v.w);
        ((ushort4*)y)[i] = o;
    }
}

// ---------------- W [K,N] fp32 -> W^T [N,K] bf16 ----------------
__global__ __launch_bounds__(256) void transpose_to_bf16_kernel(const float* __restrict__ W,
                                                                u16* __restrict__ WT, int D) {
    __shared__ float t[32][33];
    int bx = blockIdx.x, by = blockIdx.y;
    int tx = threadIdx.x, ty = threadIdx.y;
#pragma unroll
    for (int i = ty; i < 32; i += 8)
        t[i][tx] = W[(long)(by * 32 + i) * D + bx * 32 + tx];
    __syncthreads();
#pragma unroll
    for (int i = ty; i < 32; i += 8)
        WT[(long)(bx * 32 + i) * D + by * 32 + tx] = f2bf(t[tx][i]);
}

__global__ __launch_bounds__(256) void concat_bias_kernel(const float* __restrict__ a,
                                                          const float* __restrict__ b,
                                                          float* __restrict__ o, int n) {
    int i = blockIdx.x * 256 + threadIdx.x;
    if (i < 2 * n) o[i] = (i < n) ? a[i] : b[i - n];
}

// Shared epilogue pattern (both GEMMs): acc frags -> per-wave LDS slice (fp32,
// row stride 68 words: 16B-aligned float4s, fq-groups land on distinct banks)
// -> coalesced 16B reads -> scale/bias/mask applied VECTORIZED -> 16B global
// stores. Replaces 64 scalar stores + 64 scalar mask loads per thread with
// 16 float4 store-equivalents.

// ================= 256x128-tile GEMM, 512 thr, BK=32, dbuf 48 KB =================
// Demand/(FLOP) 25% lower than 128^2; 2 blocks/CU (LDS 48 KB, regs ~120).
__global__ __launch_bounds__(512, 4) void gemm_wide_kernel(
    const u16* __restrict__ A, int lda, long sA,
    const u16* __restrict__ B, int ldb, long sB,
    void* __restrict__ C, int ldc, long sC, int c_bf16,
    const float* __restrict__ bias, int bias_mode,
    const float* __restrict__ madd, int mask_ld,
    float scale, int K) {
    __shared__ __align__(16) u16 SMEM[2][384 * 32];  // As 256*32 + Bs 128*32 per buf
    const int bz = blockIdx.z;
    const u16* Ab = A + (long)bz * sA;
    const u16* Bb = B + (long)bz * sB;
    const int tm = blockIdx.y * 256, tn = blockIdx.x * 128;
    const int tid = threadIdx.x, wave = tid >> 6, lane = tid & 63;
    const int wm = (wave & 3) * 64, wn = (wave >> 2) * 64;
    const int lr = lane >> 2, c = lane & 3;
    const int fm = lane & 15, fq = lane >> 4;

    f32x4 acc[4][4];
#pragma unroll
    for (int i = 0; i < 4; i++)
#pragma unroll
        for (int j = 0; j < 4; j++) acc[i][j] = (f32x4){0.f, 0.f, 0.f, 0.f};

    const int T = K >> 5;

    auto stage = [&](int t, int buf) {
        u16* As = &SMEM[buf][0];
        u16* Bs = &SMEM[buf][256 * 32];
#pragma unroll
        for (int r = 0; r < 2; r++) {
            const int rl = wave * 32 + r * 16;
            const int row = rl + lr;
            const int kc = (t << 5) + ((c ^ ((row ^ (row >> 2)) & 3)) << 3);
            const u16* ga = Ab + (long)(tm + row) * lda + kc;
            __builtin_amdgcn_global_load_lds((const __attribute__((address_space(1))) void*)ga,
                                             (__attribute__((address_space(3))) void*)&As[rl * 32],
                                             16, 0, 0);
        }
        {
            const int rl = wave * 16;
            const int row = rl + lr;
            const int kc = (t << 5) + ((c ^ ((row ^ (row >> 2)) & 3)) << 3);
            const u16* gb = Bb + (long)(tn + row) * ldb + kc;
            __builtin_amdgcn_global_load_lds((const __attribute__((address_space(1))) void*)gb,
                                             (__attribute__((address_space(3))) void*)&Bs[rl * 32],
                                             16, 0, 0);
        }
    };

    stage(0, 0);
    __syncthreads();
    for (int t = 0; t < T; t++) {
        const int cur = t & 1;
        if (t + 1 < T) stage(t + 1, cur ^ 1);
        const u16* As = &SMEM[cur][0];
        const u16* Bs = &SMEM[cur][256 * 32];
        bf16x8 af[4], bfr[4];
#pragma unroll
        for (int i = 0; i < 4; i++) {
            int row = wm + i * 16 + fm;
            af[i] = *(const bf16x8*)&As[row * 32 + ((fq ^ ((row ^ (row >> 2)) & 3)) << 3)];
        }
#pragma unroll
        for (int j = 0; j < 4; j++) {
            int row = wn + j * 16 + fm;
            bfr[j] = *(const bf16x8*)&Bs[row * 32 + ((fq ^ ((row ^ (row >> 2)) & 3)) << 3)];
        }
#pragma unroll
        for (int i = 0; i < 4; i++)
#pragma unroll
            for (int j = 0; j < 4; j++)
                acc[i][j] = __builtin_amdgcn_mfma_f32_16x16x32_bf16(af[i], bfr[j], acc[i][j], 0, 0, 0);
        if (t + 1 < T) __syncthreads();
    }
    __syncthreads();  // all frag reads done before LDS reuse as epilogue staging

    float* EP = (float*)&SMEM[0][0] + wave * 1088;  // 16 rows x stride 68
    const int row16 = lane >> 2, cb = (lane & 3) * 16;
    float4 bc[4];
    if (bias_mode == 1) {
#pragma unroll
        for (int q = 0; q < 4; q++) bc[q] = *(const float4*)&bias[tn + wn + cb + q * 4];
    }
#pragma unroll
    for (int i = 0; i < 4; i++) {
#pragma unroll
        for (int j = 0; j < 4; j++)
#pragma unroll
            for (int r = 0; r < 4; r++)
                EP[(fq * 4 + r) * 68 + j * 16 + fm] = acc[i][j][r];
        const long grow = tm + wm + i * 16 + row16;
        float rb = (bias_mode == 2) ? bias[grow] : 0.f;
        float4 t4[4];
#pragma unroll
        for (int q = 0; q < 4; q++) {
            float4 v = *(const float4*)&EP[row16 * 68 + cb + q * 4];
            v.x = v.x * scale + rb; v.y = v.y * scale + rb;
            v.z = v.z * scale + rb; v.w = v.w * scale + rb;
            if (bias_mode == 1) { v.x += bc[q].x; v.y += bc[q].y; v.z += bc[q].z; v.w += bc[q].w; }
            if (madd) {
                float4 m4 = *(const float4*)&madd[grow * mask_ld + tn + wn + cb + q * 4];
                v.x += m4.x; v.y += m4.y; v.z += m4.z; v.w += m4.w;
            }
            t4[q] = v;
        }
        if (c_bf16) {
            u16* dst = (u16*)C + (long)bz * sC + grow * ldc + tn + wn + cb;
            uint4 o0 = {pack2(t4[0].x, t4[0].y), pack2(t4[0].z, t4[0].w),
                        pack2(t4[1].x, t4[1].y), pack2(t4[1].z, t4[1].w)};
            uint4 o1 = {pack2(t4[2].x, t4[2].y), pack2(t4[2].z, t4[2].w),
                        pack2(t4[3].x, t4[3].y), pack2(t4[3].z, t4[3].w)};
            *(uint4*)dst = o0;
            *(uint4*)(dst + 8) = o1;
        } else {
            float* dst = (float*)C + (long)bz * sC + grow * ldc + tn + wn + cb;
#pragma unroll
            for (int q = 0; q < 4; q++) *(float4*)(dst + q * 4) = t4[q];
        }
    }
}

// ================= 128x128-tile GEMM, BK=32, dbuf 32 KB, 4 blocks/CU (R4) =================
__global__ __launch_bounds__(256, 4) void gemm_bt_kernel(
    const u16* __restrict__ A, int lda, long sA,
    const u16* __restrict__ B, int ldb, long sB,
    void* __restrict__ C, int ldc, long sC, int c_bf16,
    const float* __restrict__ bias, int bias_mode,
    const float* __restrict__ madd, int mask_ld,
    float scale, int K) {
    __shared__ __align__(16) u16 SMEM[2][256 * 32];  // As 128*32 + Bs 128*32 per buf
    const int bz = blockIdx.z;
    const u16* Ab = A + (long)bz * sA;
    const u16* Bb = B + (long)bz * sB;
    const int tm = blockIdx.y * 128, tn = blockIdx.x * 128;
    const int tid = threadIdx.x, wave = tid >> 6, lane = tid & 63;
    const int wm = (wave >> 1) * 64, wn = (wave & 1) * 64;
    const int lr = lane >> 2, c = lane & 3;
    const int fm = lane & 15, fq = lane >> 4;

    f32x4 acc[4][4];
#pragma unroll
    for (int i = 0; i < 4; i++)
#pragma unroll
        for (int j = 0; j < 4; j++) acc[i][j] = (f32x4){0.f, 0.f, 0.f, 0.f};

    const int T = K >> 5;

    auto stage = [&](int t, int buf) {
        u16* As = &SMEM[buf][0];
        u16* Bs = &SMEM[buf][128 * 32];
#pragma unroll
        for (int r = 0; r < 2; r++) {
            const int rl = r * 64 + wave * 16;
            const int row = rl + lr;
            const int kc = (t << 5) + ((c ^ ((row ^ (row >> 2)) & 3)) << 3);
            const u16* ga = Ab + (long)(tm + row) * lda + kc;
            const u16* gb = Bb + (long)(tn + row) * ldb + kc;
            __builtin_amdgcn_global_load_lds((const __attribute__((address_space(1))) void*)ga,
                                             (__attribute__((address_space(3))) void*)&As[rl * 32],
                                             16, 0, 0);
            __builtin_amdgcn_global_load_lds((const __attribute__((address_space(1))) void*)gb,
                                             (__attribute__((address_space(3))) void*)&Bs[rl * 32],
                                             16, 0, 0);
        }
    };

    stage(0, 0);
    __syncthreads();
    for (int t = 0; t < T; t++) {
        const int cur = t & 1;
        if (t + 1 < T) stage(t + 1, cur ^ 1);
        const u16* As = &SMEM[cur][0];
        const u16* Bs = &SMEM[cur][128 * 32];
        bf16x8 af[4], bfr[4];
#pragma unroll
        for (int i = 0; i < 4; i++) {
            int row = wm + i * 16 + fm;
            af[i] = *(const bf16x8*)&As[row * 32 + ((fq ^ ((row ^ (row >> 2)) & 3)) << 3)];
        }
#pragma unroll
        for (int j = 0; j < 4; j++) {
            int row = wn + j * 16 + fm;
            bfr[j] = *(const bf16x8*)&Bs[row * 32 + ((fq ^ ((row ^ (row >> 2)) & 3)) << 3)];
        }
#pragma unroll
        for (int i = 0; i < 4; i++)
#pragma unroll
            for (int j = 0; j < 4; j++)
                acc[i][j] = __builtin_amdgcn_mfma_f32_16x16x32_bf16(af[i], bfr[j], acc[i][j], 0, 0, 0);
        if (t + 1 < T) __syncthreads();
    }
    __syncthreads();

    float* EP = (float*)&SMEM[0][0] + wave * 1088;
    const int row16 = lane >> 2, cb = (lane & 3) * 16;
    float4 bc[4];
    if (bias_mode == 1) {
#pragma unroll
        for (int q = 0; q < 4; q++) bc[q] = *(const float4*)&bias[tn + wn + cb + q * 4];
    }
#pragma unroll
    for (int i = 0; i < 4; i++) {
#pragma unroll
        for (int j = 0; j < 4; j++)
#pragma unroll
            for (int r = 0; r < 4; r++)
                EP[(fq * 4 + r) * 68 + j * 16 + fm] = acc[i][j][r];
        const long grow = tm + wm + i * 16 + row16;
        float rb = (bias_mode == 2) ? bias[grow] : 0.f;
        float4 t4[4];
#pragma unroll
        for (int q = 0; q < 4; q++) {
            float4 v = *(const float4*)&EP[row16 * 68 + cb + q * 4];
            v.x = v.x * scale + rb; v.y = v.y * scale + rb;
            v.z = v.z * scale + rb; v.w = v.w * scale + rb;
            if (bias_mode == 1) { v.x += bc[q].x; v.y += bc[q].y; v.z += bc[q].z; v.w += bc[q].w; }
            if (madd) {
                float4 m4 = *(const float4*)&madd[grow * mask_ld + tn + wn + cb + q * 4];
                v.x += m4.x; v.y += m4.y; v.z += m4.z; v.w += m4.w;
            }
            t4[q] = v;
        }
        if (c_bf16) {
            u16* dst = (u16*)C + (long)bz * sC + grow * ldc + tn + wn + cb;
            uint4 o0 = {pack2(t4[0].x, t4[0].y), pack2(t4[0].z, t4[0].w),
                        pack2(t4[1].x, t4[1].y), pack2(t4[1].z, t4[1].w)};
            uint4 o1 = {pack2(t4[2].x, t4[2].y), pack2(t4[2].z, t4[2].w),
                        pack2(t4[3].x, t4[3].y), pack2(t4[3].z, t4[3].w)};
            *(uint4*)dst = o0;
            *(uint4*)(dst + 8) = o1;
        } else {
            float* dst = (float*)C + (long)bz * sC + grow * ldc + tn + wn + cb;
#pragma unroll
            for (int q = 0; q < 4; q++) *(float4*)(dst + q * 4) = t4[q];
        }
    }
}

// ---------------- in-place row softmax over 2048 bf16 cols ----------------
__global__ __launch_bounds__(256) void softmax_kernel(u16* __restrict__ s) {
    const long row = blockIdx.x;
    u16* p = s + row * 2048;
    const int tid = threadIdx.x;
    const int lane = tid & 63, wave = tid >> 6;
    __shared__ float redm[4], reds[4];

    uint4 raw = ((const uint4*)p)[tid];
    float v[8];
    v[0] = bf2f(raw.x & 0xffff); v[1] = bf2f(raw.x >> 16);
    v[2] = bf2f(raw.y & 0xffff); v[3] = bf2f(raw.y >> 16);
    v[4] = bf2f(raw.z & 0xffff); v[5] = bf2f(raw.z >> 16);
    v[6] = bf2f(raw.w & 0xffff); v[7] = bf2f(raw.w >> 16);

    float m = v[0];
#pragma unroll
    for (int k = 1; k < 8; k++) m = fmaxf(m, v[k]);
#pragma unroll
    for (int off = 32; off; off >>= 1) m = fmaxf(m, __shfl_xor(m, off));
    if (lane == 0) redm[wave] = m;
    __syncthreads();
    m = fmaxf(fmaxf(redm[0], redm[1]), fmaxf(redm[2], redm[3]));

    float sum = 0.f;
#pragma unroll
    for (int k = 0; k < 8; k++) { v[k] = __expf(v[k] - m); sum += v[k]; }
#pragma unroll
    for (int off = 32; off; off >>= 1) sum += __shfl_xor(sum, off);
    if (lane == 0) reds[wave] = sum;
    __syncthreads();
    sum = reds[0] + reds[1] + reds[2] + reds[3];
    float inv = 1.f / sum;

    uint4 o;
    o.x = pack2(v[0] * inv, v[1] * inv);
    o.y = pack2(v[2] * inv, v[3] * inv);
    o.z = pack2(v[4] * inv, v[5] * inv);
    o.w = pack2(v[6] * inv, v[7] * inv);
    ((uint4*)p)[tid] = o;
}

extern "C" void kernel_launch(void* const* d_in, const int* in_sizes, int n_in,
                              void* d_out, int out_size, void* d_ws, size_t ws_size,
                              hipStream_t stream) {
    const float* x    = (const float*)d_in[0];
    const float* mask = (const float*)d_in[1];
    const float* Wq   = (const float*)d_in[2];
    const float* bq   = (const float*)d_in[3];
    const float* Wk   = (const float*)d_in[4];
    const float* bk   = (const float*)d_in[5];
    const float* Wv   = (const float*)d_in[6];
    const float* bv   = (const float*)d_in[7];
    float* out = (float*)d_out;

    const int B = 4, S = 2048, D = 1024;
    const long MS = (long)B * S;  // 8192

    size_t need = (size_t)MS * D * 2 + (size_t)(2 * D) * D * 2 + (size_t)D * D * 2
                + (size_t)(2 * D) * 4 + (size_t)MS * (2 * D) * 2 + (size_t)D * MS * 2
                + (size_t)B * S * S * 2;
    if (ws_size < need) return;

    char* ws = (char*)d_ws;
    u16*  xb   = (u16*)ws;  ws += (long)MS * D * 2;
    u16*  wqkt = (u16*)ws;  ws += (long)(2 * D) * D * 2;
    u16*  wvt  = (u16*)ws;  ws += (long)D * D * 2;
    float* bqk = (float*)ws; ws += (long)(2 * D) * 4;
    u16*  QK   = (u16*)ws;  ws += (long)MS * (2 * D) * 2;
    u16*  VT   = (u16*)ws;  ws += (long)D * MS * 2;
    u16*  sc   = (u16*)ws;  ws += (long)B * S * S * 2;

    const float SCALE = 0.03125f;  // 1/sqrt(1024)

    convert_bf16_kernel<<<(int)((MS * D / 4 + 255) / 256), 256, 0, stream>>>(x, xb, (int)(MS * D / 4));
    dim3 tb(32, 8);
    transpose_to_bf16_kernel<<<dim3(32, 32), tb, 0, stream>>>(Wq, wqkt, D);
    transpose_to_bf16_kernel<<<dim3(32, 32), tb, 0, stream>>>(Wk, wqkt + (long)D * D, D);
    transpose_to_bf16_kernel<<<dim3(32, 32), tb, 0, stream>>>(Wv, wvt, D);
    concat_bias_kernel<<<8, 256, 0, stream>>>(bq, bk, bqk, D);

    // QK projection: [8192, 2048] bf16, 256x128 tiles -> grid (16, 32), 512 blocks
    gemm_wide_kernel<<<dim3(2 * D / 128, (int)(MS / 256), 1), 512, 0, stream>>>(
        xb, D, 0, wqkt, D, 0, QK, 2 * D, 0, 1, bqk, 1, nullptr, 0, 1.0f, D);
    // V^T [1024, 8192] bf16: 128^2 tiles (kept: wide tile would drop to 1 block/CU grid)
    gemm_bt_kernel<<<dim3((int)(MS / 128), D / 128, 1), 256, 0, stream>>>(
        wvt, D, 0, xb, D, 0, VT, (int)MS, 0, 1, bv, 2, nullptr, 0, 1.0f, D);

    // scores: 256x128 tiles -> grid (16, 8, 4), 512 blocks
    gemm_wide_kernel<<<dim3(S / 128, S / 256, B), 512, 0, stream>>>(
        QK, 2 * D, (long)S * 2 * D, QK + D, 2 * D, (long)S * 2 * D, sc, S, (long)S * S, 1,
        nullptr, 0, mask, S, SCALE, D);

    softmax_kernel<<<B * S, 256, 0, stream>>>(sc);

    // PV: 128^2 tiles (grid (8,16,4) = 512 blocks)
    gemm_bt_kernel<<<dim3(D / 128, S / 128, B), 256, 0, stream>>>(
        sc, S, (long)S * S, VT, (int)MS, (long)S, out, D, (long)S * D, 0,
        nullptr, 0, nullptr, 0, 1.0f, S);
}